// Round 8
// baseline (881.574 us; speedup 1.0000x reference)
//
#include <hip/hip_runtime.h>
#include <hip/hip_bf16.h>

// ---------------------------------------------------------------------------
// GCNRegression: 4x (GEMM 128x128 + symmetric-norm aggregation + ReLU),
// then global mean pool (128 graphs) + FC(128->1).
//
// R7 notes:
//  - agg latency-bound: ~40 outstanding gathers/CU, 4.9 cyc/gather. -> 8
//    independent gather chains (32 edges/node/iter), indices prefetched a
//    full iteration ahead, all 8 loads issued before first use.
//  - gemm suspected latency-stalled on A-loads with ~4 waves/SIMD. -> 2x4
//    thread tile (64-row blocks, grid 3128), VGPR ~70 -> ~7 waves/SIMD.
// ---------------------------------------------------------------------------

// ---- degree histogram (single pass, int4 reads) ---------------------------
__global__ void count_deg_kernel(const int* __restrict__ dst, int* __restrict__ deg, int E) {
    int i = blockIdx.x * blockDim.x + threadIdx.x;
    int e = i * 4;
    if (e + 3 < E) {
        int4 d = *(const int4*)(dst + e);
        atomicAdd(&deg[d.x], 1);
        atomicAdd(&deg[d.y], 1);
        atomicAdd(&deg[d.z], 1);
        atomicAdd(&deg[d.w], 1);
    } else {
        for (; e < E; e++) atomicAdd(&deg[dst[e]], 1);
    }
}

// ---- dinv = 1/sqrt(deg+1) -------------------------------------------------
__global__ void dinv_kernel(const int* __restrict__ deg, float* __restrict__ dinv, int n) {
    int i = blockIdx.x * blockDim.x + threadIdx.x;
    if (i < n) dinv[i] = (float)(1.0 / sqrt((double)(deg[i] + 1)));
}

// ---- single-block exclusive scan -> row_ptr -------------------------------
__global__ void scan_kernel(const int* __restrict__ cnt, int* __restrict__ row_ptr, int n) {
    __shared__ int sums[1024];
    int t = threadIdx.x;
    int per = (n + 1023) >> 10;
    int s = t * per;
    int e = s + per; if (e > n) e = n; if (s > n) s = n;
    int acc = 0;
    for (int i = s; i < e; i++) acc += cnt[i];
    sums[t] = acc;
    __syncthreads();
    for (int off = 1; off < 1024; off <<= 1) {
        int u = (t >= off) ? sums[t - off] : 0;
        __syncthreads();
        sums[t] += u;
        __syncthreads();
    }
    int excl = sums[t] - acc;
    int run = excl;
    for (int i = s; i < e; i++) { row_ptr[i] = run; run += cnt[i]; }
    if (t == 1023) row_ptr[n] = sums[1023];
}

// ---- CSR fill (uint16 src), XCD-range-partitioned -------------------------
__global__ __launch_bounds__(256) void csr_fill_kernel(const int* __restrict__ src,
                                                       const int* __restrict__ dst,
                                                       const int* __restrict__ row_ptr,
                                                       int* __restrict__ fill,
                                                       unsigned short* __restrict__ csr_src,
                                                       int E, int N) {
    int g  = blockIdx.x & 7;
    int gb = blockIdx.x >> 3;
    int group_blocks = gridDim.x >> 3;
    int R  = (N + 7) >> 3;
    int lo = g * R;
    int hi = lo + R; if (hi > N) hi = N;

    int tig    = gb * blockDim.x + threadIdx.x;
    int stride = group_blocks * blockDim.x;
    int nq = (E + 3) >> 2;

    for (int q = tig; q < nq; q += stride) {
        int e = q * 4;
        if (e + 3 < E) {
            int4 d = *(const int4*)(dst + e);
            if (d.x >= lo && d.x < hi) {
                int pos = row_ptr[d.x] + atomicAdd(&fill[d.x], 1);
                csr_src[pos] = (unsigned short)src[e + 0];
            }
            if (d.y >= lo && d.y < hi) {
                int pos = row_ptr[d.y] + atomicAdd(&fill[d.y], 1);
                csr_src[pos] = (unsigned short)src[e + 1];
            }
            if (d.z >= lo && d.z < hi) {
                int pos = row_ptr[d.z] + atomicAdd(&fill[d.z], 1);
                csr_src[pos] = (unsigned short)src[e + 2];
            }
            if (d.w >= lo && d.w < hi) {
                int pos = row_ptr[d.w] + atomicAdd(&fill[d.w], 1);
                csr_src[pos] = (unsigned short)src[e + 3];
            }
        } else {
            for (; e < E; e++) {
                int d = dst[e];
                if (d >= lo && d < hi) {
                    int pos = row_ptr[d] + atomicAdd(&fill[d], 1);
                    csr_src[pos] = (unsigned short)src[e];
                }
            }
        }
    }
}

// ---- GEMM: C = (A @ W) * dinv[row], C channel-blocked [8][n][16] ----------
// 64 rows x 32 cols per 256-thread block; W quarter (16KB) in LDS.
// Per thread 2 rows x 4 cols (low VGPR -> high occupancy for latency hiding).
// A pointer-incremented per 16-k block:
//   non-blocked (row-major [n][128]): stage s at A+rr*128+16s  -> bump 16
//   blocked     ([8][n][16]):         stage s at A+(s*n+rr)*16 -> bump n*16
__global__ __launch_bounds__(256) void gemm_kernel(const float* __restrict__ A,
                                                   const float* __restrict__ W,
                                                   const float* __restrict__ dinv,
                                                   float* __restrict__ C, int n,
                                                   int a_blocked) {
    __shared__ float sW[128 * 32];
    int t = threadIdx.x;
    int col0 = (blockIdx.x & 3) * 32;
    int row0 = (blockIdx.x >> 2) * 64;

    #pragma unroll
    for (int i = 0; i < 4; i++) {
        int fidx = t + 256 * i;            // 1024 float4
        int k  = fidx >> 3;
        int c4 = fidx & 7;
        *(float4*)(sW + k * 32 + c4 * 4) =
            *(const float4*)(W + (size_t)k * 128 + col0 + c4 * 4);
    }
    __syncthreads();

    int cg = (t & 7) * 4;          // 4 cols within the 32-col tile
    int rg = (t >> 3) * 2;         // 2 rows
    int rbase = row0 + rg;

    const float* ap[2];
    #pragma unroll
    for (int r = 0; r < 2; r++) {
        int rr = rbase + r; if (rr > n - 1) rr = n - 1;   // clamp (store guarded)
        ap[r] = a_blocked ? (A + (size_t)rr * 16) : (A + (size_t)rr * 128);
    }
    size_t bump = a_blocked ? (size_t)n * 16 : (size_t)16;

    float acc[2][4];
    #pragma unroll
    for (int r = 0; r < 2; r++)
        #pragma unroll
        for (int c = 0; c < 4; c++) acc[r][c] = 0.f;

    // bufA holds k = kb*16+0..7, bufB holds k = kb*16+8..15
    float4 bufA[2][2], bufB[2][2];
    #pragma unroll
    for (int r = 0; r < 2; r++) {
        bufA[r][0] = *(const float4*)(ap[r] + 0);
        bufA[r][1] = *(const float4*)(ap[r] + 4);
        bufB[r][0] = *(const float4*)(ap[r] + 8);
        bufB[r][1] = *(const float4*)(ap[r] + 12);
        ap[r] += bump;
    }

    #pragma unroll 1
    for (int kb = 0; kb < 8; kb++) {
        const float* wrow = sW + kb * 16 * 32 + cg;
        #pragma unroll
        for (int kk = 0; kk < 8; kk++) {
            float4 w = *(const float4*)(wrow + kk * 32);
            #pragma unroll
            for (int r = 0; r < 2; r++) {
                float4 aq = bufA[r][kk >> 2];
                float av = ((kk & 3) == 0) ? aq.x : ((kk & 3) == 1) ? aq.y
                         : ((kk & 3) == 2) ? aq.z : aq.w;
                acc[r][0] = fmaf(av, w.x, acc[r][0]);
                acc[r][1] = fmaf(av, w.y, acc[r][1]);
                acc[r][2] = fmaf(av, w.z, acc[r][2]);
                acc[r][3] = fmaf(av, w.w, acc[r][3]);
            }
        }
        if (kb < 7) {   // reload bufA for kb+1; used after bufB compute
            #pragma unroll
            for (int r = 0; r < 2; r++) {
                bufA[r][0] = *(const float4*)(ap[r] + 0);
                bufA[r][1] = *(const float4*)(ap[r] + 4);
            }
        }
        #pragma unroll
        for (int kk = 0; kk < 8; kk++) {
            float4 w = *(const float4*)(wrow + (8 + kk) * 32);
            #pragma unroll
            for (int r = 0; r < 2; r++) {
                float4 aq = bufB[r][kk >> 2];
                float av = ((kk & 3) == 0) ? aq.x : ((kk & 3) == 1) ? aq.y
                         : ((kk & 3) == 2) ? aq.z : aq.w;
                acc[r][0] = fmaf(av, w.x, acc[r][0]);
                acc[r][1] = fmaf(av, w.y, acc[r][1]);
                acc[r][2] = fmaf(av, w.z, acc[r][2]);
                acc[r][3] = fmaf(av, w.w, acc[r][3]);
            }
        }
        if (kb < 7) {
            #pragma unroll
            for (int r = 0; r < 2; r++) {
                bufB[r][0] = *(const float4*)(ap[r] + 8);
                bufB[r][1] = *(const float4*)(ap[r] + 12);
                ap[r] += bump;
            }
        }
    }

    int cb = col0 + cg;
    float* Cb = C + (size_t)(cb >> 4) * n * 16 + (cb & 15);
    #pragma unroll
    for (int r = 0; r < 2; r++) {
        int rr = rbase + r;
        if (rr < n) {
            float dsc = dinv[rr];
            *(float4*)(Cb + (size_t)rr * 16) =
                make_float4(acc[r][0] * dsc, acc[r][1] * dsc,
                            acc[r][2] * dsc, acc[r][3] * dsc);
        }
    }
}

// ---- Aggregation, channel-sliced, 8 gather chains + csr prefetch ----------
// h holds pre-scaled rows (h*dinv[row]) blocked [8][n][16].
// out[i] = relu( (sum_edges slice[src] + slice[i]) * dinv[i] + b )
__global__ __launch_bounds__(256) void agg_kernel(const float* __restrict__ h,
                                                  const int* __restrict__ row_ptr,
                                                  const unsigned short* __restrict__ csr_src,
                                                  const float* __restrict__ dinv,
                                                  const float* __restrict__ bias,
                                                  float* __restrict__ out, int n) {
    int p     = blockIdx.x & 7;
    int chunk = blockIdx.x >> 3;
    int wave  = threadIdx.x >> 6;
    int lane  = threadIdx.x & 63;
    int sub   = lane >> 4;          // node within wave
    int es    = (lane >> 2) & 3;    // edge slot
    int q     = lane & 3;           // channel quad
    int i = chunk * 16 + wave * 4 + sub;
    bool valid = (i < n);
    int iv = valid ? i : 0;

    const float* slice  = h   + (size_t)p * n * 16;
    float*       oslice = out + (size_t)p * n * 16;

    int beg = row_ptr[iv];
    int end = valid ? row_ptr[iv + 1] : beg;

    float4 acc = make_float4(0.f, 0.f, 0.f, 0.f);
    int qoff = q << 2;

    // 8 chains at e+0,4,...,28; step 32. Indices prefetched one full
    // iteration ahead; all 8 gathers issued before the first use.
    int e = beg + es;
    int s[8];
    #pragma unroll
    for (int c = 0; c < 8; c++)
        s[c] = (e + 4 * c < end) ? (int)__builtin_nontemporal_load(csr_src + e + 4 * c) : -1;

    while (__any(e < end)) {
        int en = e + 32;
        int nx[8];
        #pragma unroll
        for (int c = 0; c < 8; c++)
            nx[c] = (en + 4 * c < end) ? (int)__builtin_nontemporal_load(csr_src + en + 4 * c) : -1;

        float wgt[8]; int g[8];
        #pragma unroll
        for (int c = 0; c < 8; c++) {
            wgt[c] = (s[c] >= 0) ? 1.f : 0.f;
            g[c]   = (s[c] >= 0) ? s[c] : 0;
        }
        float4 v[8];
        #pragma unroll
        for (int c = 0; c < 8; c++)
            v[c] = *(const float4*)(slice + (g[c] << 4) + qoff);
        #pragma unroll
        for (int c = 0; c < 8; c++) {
            acc.x = fmaf(v[c].x, wgt[c], acc.x);
            acc.y = fmaf(v[c].y, wgt[c], acc.y);
            acc.z = fmaf(v[c].z, wgt[c], acc.z);
            acc.w = fmaf(v[c].w, wgt[c], acc.w);
        }

        e = en;
        #pragma unroll
        for (int c = 0; c < 8; c++) s[c] = nx[c];
    }

    acc.x += __shfl_xor(acc.x, 4);
    acc.y += __shfl_xor(acc.y, 4);
    acc.z += __shfl_xor(acc.z, 4);
    acc.w += __shfl_xor(acc.w, 4);
    acc.x += __shfl_xor(acc.x, 8);
    acc.y += __shfl_xor(acc.y, 8);
    acc.z += __shfl_xor(acc.z, 8);
    acc.w += __shfl_xor(acc.w, 8);

    float di = dinv[iv];
    float4 self = *(const float4*)(slice + (iv << 4) + qoff);
    float4 b4   = *(const float4*)(bias + p * 16 + qoff);
    float4 o;
    o.x = fmaxf(fmaf(acc.x + self.x, di, b4.x), 0.f);
    o.y = fmaxf(fmaf(acc.y + self.y, di, b4.y), 0.f);
    o.z = fmaxf(fmaf(acc.z + self.z, di, b4.z), 0.f);
    o.w = fmaxf(fmaf(acc.w + self.w, di, b4.w), 0.f);

    if (valid && es == 0)
        *(float4*)(oslice + (i << 4) + qoff) = o;
}

// ---- pool stage 1: deterministic fp64 partials, one slot per (g,s) --------
__global__ __launch_bounds__(128) void pool_partial_kernel(const float* __restrict__ h,
                                                           const int* __restrict__ batch,
                                                           double* __restrict__ partials,
                                                           int n, int S) {
    int g = blockIdx.x / S;
    int s = blockIdx.x % S;
    int c = threadIdx.x;
    const float* hb = h + ((size_t)(c >> 4) * n) * 16 + (c & 15);

    int lo = 0, hi = n;
    while (lo < hi) { int mid = (lo + hi) >> 1; if (batch[mid] < g) lo = mid + 1; else hi = mid; }
    int start = lo;
    lo = start; hi = n;
    while (lo < hi) { int mid = (lo + hi) >> 1; if (batch[mid] < g + 1) lo = mid + 1; else hi = mid; }
    int end = lo;

    int cnt = end - start;
    int per = (cnt + S - 1) / S;
    int rs = start + s * per;
    int re = rs + per; if (re > end) re = end;

    double a0 = 0.0, a1 = 0.0, a2 = 0.0, a3 = 0.0;
    int r = rs;
    for (; r + 4 <= re; r += 4) {
        a0 += (double)hb[(size_t)(r + 0) * 16];
        a1 += (double)hb[(size_t)(r + 1) * 16];
        a2 += (double)hb[(size_t)(r + 2) * 16];
        a3 += (double)hb[(size_t)(r + 3) * 16];
    }
    for (; r < re; r++) a0 += (double)hb[(size_t)r * 16];
    partials[(size_t)(g * S + s) * 128 + c] = (a0 + a1) + (a2 + a3);
}

// ---- pool stage 2: reduce S partials, mean + FC(128->1), fp64 -------------
__global__ __launch_bounds__(128) void pool_fc_final_kernel(const double* __restrict__ partials,
                                                            const int* __restrict__ batch,
                                                            const float* __restrict__ Wfc,
                                                            const float* __restrict__ bfc,
                                                            float* __restrict__ out,
                                                            int n, int S) {
    int g = blockIdx.x;
    int c = threadIdx.x;

    int lo = 0, hi = n;
    while (lo < hi) { int mid = (lo + hi) >> 1; if (batch[mid] < g) lo = mid + 1; else hi = mid; }
    int start = lo;
    lo = start; hi = n;
    while (lo < hi) { int mid = (lo + hi) >> 1; if (batch[mid] < g + 1) lo = mid + 1; else hi = mid; }
    int cnt = lo - start;

    double sum = 0.0;
    for (int s = 0; s < S; s++) sum += partials[(size_t)(g * S + s) * 128 + c];
    double mean = sum / (double)(cnt > 0 ? cnt : 1);
    double v = mean * (double)Wfc[c];

    __shared__ double red[128];
    red[c] = v;
    __syncthreads();
    for (int off = 64; off > 0; off >>= 1) {
        if (c < off) red[c] += red[c + off];
        __syncthreads();
    }
    if (c == 0) out[g] = (float)(red[0] + (double)bfc[0]);
}

// ---------------------------------------------------------------------------
extern "C" void kernel_launch(void* const* d_in, const int* in_sizes, int n_in,
                              void* d_out, int out_size, void* d_ws, size_t ws_size,
                              hipStream_t stream) {
    const float* x          = (const float*)d_in[0];
    const int*   edge_index = (const int*)d_in[1];
    const int*   batch      = (const int*)d_in[2];
    const float* W1  = (const float*)d_in[3];
    const float* b1  = (const float*)d_in[4];
    const float* W2  = (const float*)d_in[5];
    const float* b2  = (const float*)d_in[6];
    const float* Wfc = (const float*)d_in[7];
    const float* bfc = (const float*)d_in[8];
    float* out = (float*)d_out;

    const int N = in_sizes[2];       // 50000
    const int E = in_sizes[1] / 2;   // 1600000
    const int G = out_size;          // 128 graphs

    const int* e_src = edge_index;
    const int* e_dst = edge_index + E;

    char* p = (char*)d_ws;
    auto alloc = [&](size_t bytes) {
        void* r = (void*)p;
        p += (bytes + 255) & ~(size_t)255;
        return r;
    };
    const int S = 8;
    float*          h0        = (float*)alloc((size_t)N * 128 * 4);
    float*          h1        = (float*)alloc((size_t)N * 128 * 4);
    unsigned short* csr_src   = (unsigned short*)alloc((size_t)E * 2);
    int*            row_ptr   = (int*)  alloc((size_t)(N + 1) * 4);
    int*            deg_cnt   = (int*)  alloc((size_t)N * 4);
    int*            fill      = (int*)  alloc((size_t)N * 4);
    float*          dinv      = (float*)alloc((size_t)N * 4);
    double*         partials  = (double*)alloc((size_t)G * S * 128 * 8);
    (void)ws_size; (void)n_in;

    hipMemsetAsync(deg_cnt, 0, (size_t)N * 4, stream);
    hipMemsetAsync(fill,    0, (size_t)N * 4, stream);

    int tb = 256;
    int e4 = (E + 3) / 4;
    count_deg_kernel<<<(e4 + tb - 1) / tb, tb, 0, stream>>>(e_dst, deg_cnt, E);
    dinv_kernel<<<(N + tb - 1) / tb, tb, 0, stream>>>(deg_cnt, dinv, N);
    scan_kernel<<<1, 1024, 0, stream>>>(deg_cnt, row_ptr, N);
    csr_fill_kernel<<<1024, tb, 0, stream>>>(e_src, e_dst, row_ptr, fill, csr_src, E, N);

    int gemm_blocks = 4 * ((N + 63) / 64);
    int agg_blocks  = 8 * ((N + 15) / 16);

    gemm_kernel<<<gemm_blocks, 256, 0, stream>>>(x, W1, dinv, h1, N, 0);
    agg_kernel<<<agg_blocks, 256, 0, stream>>>(h1, row_ptr, csr_src, dinv, b1, h0, N);

    for (int l = 0; l < 3; l++) {
        gemm_kernel<<<gemm_blocks, 256, 0, stream>>>(h0, W2, dinv, h1, N, 1);
        agg_kernel<<<agg_blocks, 256, 0, stream>>>(h1, row_ptr, csr_src, dinv, b2, h0, N);
    }

    pool_partial_kernel<<<G * S, 128, 0, stream>>>(h0, batch, partials, N, S);
    pool_fc_final_kernel<<<G, 128, 0, stream>>>(partials, batch, Wfc, bfc, out, N, S);
}